// Round 4
// baseline (863.451 us; speedup 1.0000x reference)
//
#include <hip/hip_runtime.h>

#define N_NODES 100000
#define D 64
#define N_EDGES 1200000
#define NBKT 1563            // ceil(100000 / 64) buckets of 64 dst-nodes

// ---------- bucket histogram: bhist[dst>>6]++ ----------
__global__ __launch_bounds__(256) void bin_hist(
    const int* __restrict__ eidx, int* __restrict__ bhist)
{
    int e = blockIdx.x * blockDim.x + threadIdx.x;
    if (e >= N_EDGES) return;
    atomicAdd(&bhist[eidx[N_EDGES + e] >> 6], 1);
}

// ---------- single-block exclusive scan of 1563 bucket counts ----------
// writes boff (exclusive prefix) and cur (copy, used as fill cursors)
__global__ __launch_bounds__(256) void bscan(
    const int* __restrict__ bhist, int* __restrict__ boff, int* __restrict__ cur)
{
    __shared__ int tmp[256];
    __shared__ int carry;
    int tid = threadIdx.x;
    if (tid == 0) carry = 0;
    __syncthreads();
    for (int base = 0; base < NBKT; base += 256) {
        int i = base + tid;
        int v = (i < NBKT) ? bhist[i] : 0;
        tmp[tid] = v;
        __syncthreads();
        for (int off = 1; off < 256; off <<= 1) {
            int t = (tid >= off) ? tmp[tid - off] : 0;
            __syncthreads();
            tmp[tid] += t;
            __syncthreads();
        }
        if (i < NBKT) {
            int ex = carry + tmp[tid] - v;
            boff[i] = ex;
            cur[i]  = ex;
        }
        __syncthreads();
        if (tid == 255) carry += tmp[255];
        __syncthreads();
    }
    if (tid == 0) boff[NBKT] = N_EDGES;
}

// ---------- fill: append packed (src<<6 | dst&63) into bucket segment ----------
__global__ __launch_bounds__(256) void bin_fill(
    const int* __restrict__ eidx, int* __restrict__ cur,
    unsigned int* __restrict__ pairs)
{
    int e = blockIdx.x * blockDim.x + threadIdx.x;
    if (e >= N_EDGES) return;
    int src = eidx[e];
    int dst = eidx[N_EDGES + e];
    int pos = atomicAdd(&cur[dst >> 6], 1);
    pairs[pos] = ((unsigned int)src << 6) | (unsigned int)(dst & 63);
}

// ---------- aggregate: one block per bucket, LDS accumulator ----------
// 64 nodes x 64 dims f32 in LDS (16KB). Wave w takes edges beg+w, +4 stride;
// per edge: broadcast-load packed u32, gather feat[src][lane] (256B coalesced),
// ds_add_f32 into acc. Writes the mean directly to out.
__global__ __launch_bounds__(256) void agg_bucket(
    const float* __restrict__ feat,
    const int* __restrict__ boff,
    const unsigned int* __restrict__ pairs,
    float* __restrict__ out)
{
    __shared__ float acc[64 * 64];
    __shared__ int ldeg[64];

    const int tid  = threadIdx.x;
    const int lane = tid & 63;
    const int wv   = tid >> 6;
    const int b    = blockIdx.x;

    #pragma unroll
    for (int i = 0; i < 16; ++i) acc[tid + i * 256] = 0.0f;
    if (tid < 64) ldeg[tid] = 0;
    __syncthreads();

    const int beg = boff[b];
    const int end = boff[b + 1];

    int e = beg + wv;
    // 4 edges in flight per wave
    for (; e + 12 < end; e += 16) {
        unsigned int v0 = pairs[e];
        unsigned int v1 = pairs[e + 4];
        unsigned int v2 = pairs[e + 8];
        unsigned int v3 = pairs[e + 12];
        float f0 = feat[(size_t)(v0 >> 6) * D + lane];
        float f1 = feat[(size_t)(v1 >> 6) * D + lane];
        float f2 = feat[(size_t)(v2 >> 6) * D + lane];
        float f3 = feat[(size_t)(v3 >> 6) * D + lane];
        if (lane == 0) {
            atomicAdd(&ldeg[v0 & 63], 1);
            atomicAdd(&ldeg[v1 & 63], 1);
            atomicAdd(&ldeg[v2 & 63], 1);
            atomicAdd(&ldeg[v3 & 63], 1);
        }
        atomicAdd(&acc[(v0 & 63) * D + lane], f0);
        atomicAdd(&acc[(v1 & 63) * D + lane], f1);
        atomicAdd(&acc[(v2 & 63) * D + lane], f2);
        atomicAdd(&acc[(v3 & 63) * D + lane], f3);
    }
    for (; e < end; e += 4) {
        unsigned int v = pairs[e];
        float f = feat[(size_t)(v >> 6) * D + lane];
        if (lane == 0) atomicAdd(&ldeg[v & 63], 1);
        atomicAdd(&acc[(v & 63) * D + lane], f);
    }
    __syncthreads();

    const int nbase = b * 64;
    #pragma unroll
    for (int i = 0; i < 16; ++i) {
        int idx  = tid + i * 256;        // 0..4095
        int node = idx >> 6;
        int gn   = nbase + node;
        if (gn < N_NODES) {
            float d = (float)ldeg[node];
            d = d > 1.0f ? d : 1.0f;
            out[(size_t)gn * D + (idx & 63)] = acc[idx] / d;
        }
    }
}

// ---------- fused linear: LDS-tiled GEMM, block = 64 nodes x 64 cols ----------
#define XS 132
__global__ __launch_bounds__(256) void sage_gemm(
    const float* __restrict__ feat,
    const float* __restrict__ W,
    const float* __restrict__ bias,
    float* __restrict__ out)
{
    __shared__ float X[64 * XS];
    __shared__ float Ws[128 * 64];

    const int tid = threadIdx.x;
    const int nb  = blockIdx.x * 64;

    {
        const float4* Wv  = (const float4*)W;
        float4* Wsv = (float4*)Ws;
        #pragma unroll
        for (int r = 0; r < 8; ++r)
            Wsv[r * 256 + tid] = Wv[r * 256 + tid];
    }
    {
        const int sn = tid >> 4;
        const int kc = tid & 15;
        #pragma unroll
        for (int r = 0; r < 4; ++r) {
            int node = r * 16 + sn;
            int gn = nb + node;
            float4 f = make_float4(0.f, 0.f, 0.f, 0.f);
            float4 m = make_float4(0.f, 0.f, 0.f, 0.f);
            if (gn < N_NODES) {
                f = *(const float4*)(feat + (size_t)gn * 64 + kc * 4);
                m = *(const float4*)(out  + (size_t)gn * 64 + kc * 4);
            }
            *(float4*)(X + node * XS + kc * 4)      = f;
            *(float4*)(X + node * XS + 64 + kc * 4) = m;
        }
    }
    __syncthreads();

    const int ng = tid >> 4;
    const int cg = tid & 15;

    const float4 b4 = *(const float4*)(bias + cg * 4);
    float acc[4][4];
    #pragma unroll
    for (int i = 0; i < 4; ++i) {
        acc[i][0] = b4.x; acc[i][1] = b4.y; acc[i][2] = b4.z; acc[i][3] = b4.w;
    }

    const float* x0p = X + (ng * 4 + 0) * XS;
    const float* x1p = X + (ng * 4 + 1) * XS;
    const float* x2p = X + (ng * 4 + 2) * XS;
    const float* x3p = X + (ng * 4 + 3) * XS;
    const float4* Wrow = (const float4*)Ws;

    #pragma unroll 8
    for (int k = 0; k < 128; ++k) {
        float4 w4 = Wrow[k * 16 + cg];
        float x0 = x0p[k];
        float x1 = x1p[k];
        float x2 = x2p[k];
        float x3 = x3p[k];
        acc[0][0] = fmaf(x0, w4.x, acc[0][0]);
        acc[0][1] = fmaf(x0, w4.y, acc[0][1]);
        acc[0][2] = fmaf(x0, w4.z, acc[0][2]);
        acc[0][3] = fmaf(x0, w4.w, acc[0][3]);
        acc[1][0] = fmaf(x1, w4.x, acc[1][0]);
        acc[1][1] = fmaf(x1, w4.y, acc[1][1]);
        acc[1][2] = fmaf(x1, w4.z, acc[1][2]);
        acc[1][3] = fmaf(x1, w4.w, acc[1][3]);
        acc[2][0] = fmaf(x2, w4.x, acc[2][0]);
        acc[2][1] = fmaf(x2, w4.y, acc[2][1]);
        acc[2][2] = fmaf(x2, w4.z, acc[2][2]);
        acc[2][3] = fmaf(x2, w4.w, acc[2][3]);
        acc[3][0] = fmaf(x3, w4.x, acc[3][0]);
        acc[3][1] = fmaf(x3, w4.y, acc[3][1]);
        acc[3][2] = fmaf(x3, w4.z, acc[3][2]);
        acc[3][3] = fmaf(x3, w4.w, acc[3][3]);
    }

    #pragma unroll
    for (int i = 0; i < 4; ++i) {
        int gn = nb + ng * 4 + i;
        if (gn < N_NODES) {
            float4 o = make_float4(acc[i][0], acc[i][1], acc[i][2], acc[i][3]);
            *(float4*)(out + (size_t)gn * 64 + cg * 4) = o;
        }
    }
}

extern "C" void kernel_launch(void* const* d_in, const int* in_sizes, int n_in,
                              void* d_out, int out_size, void* d_ws, size_t ws_size,
                              hipStream_t stream) {
    const float* feat = (const float*)d_in[0];
    const int*   eidx = (const int*)d_in[1];
    const float* W    = (const float*)d_in[2];
    const float* bias = (const float*)d_in[3];
    float* out = (float*)d_out;

    int* bhist = (int*)d_ws;                       // NBKT
    int* boff  = bhist + NBKT;                     // NBKT + 1
    int* cur   = boff + NBKT + 1;                  // NBKT
    unsigned int* pairs = (unsigned int*)(cur + NBKT);  // N_EDGES

    hipMemsetAsync(bhist, 0, (size_t)NBKT * sizeof(int), stream);

    bin_hist<<<(N_EDGES + 255) / 256, 256, 0, stream>>>(eidx, bhist);
    bscan<<<1, 256, 0, stream>>>(bhist, boff, cur);
    bin_fill<<<(N_EDGES + 255) / 256, 256, 0, stream>>>(eidx, cur, pairs);

    agg_bucket<<<NBKT, 256, 0, stream>>>(feat, boff, pairs, out);
    sage_gemm<<<(N_NODES + 63) / 64, 256, 0, stream>>>(feat, W, bias, out);
}

// Round 5
// 220.772 us; speedup vs baseline: 3.9110x; 3.9110x over previous
//
#include <hip/hip_runtime.h>

#define N_NODES 100000
#define D 64
#define N_EDGES 1200000
#define NBKT 1563            // ceil(100000/64) coarse buckets (64 dst nodes each)
#define PAD 16               // pad atomic counters to one per 64B line
#define FSB ((NBKT + 3) / 4) // 391 fine-sort blocks, 4 buckets each

// ---------- coarse histogram (LDS-staged, padded global flush) ----------
__global__ __launch_bounds__(256) void bin_hist(
    const int* __restrict__ eidx, int* __restrict__ bhistP)
{
    __shared__ int lh[NBKT];
    for (int i = threadIdx.x; i < NBKT; i += 256) lh[i] = 0;
    __syncthreads();
    for (int e = blockIdx.x * 256 + threadIdx.x; e < N_EDGES; e += gridDim.x * 256)
        atomicAdd(&lh[eidx[N_EDGES + e] >> 6], 1);
    __syncthreads();
    for (int i = threadIdx.x; i < NBKT; i += 256) {
        int v = lh[i];
        if (v) atomicAdd(&bhistP[i * PAD], v);
    }
}

// ---------- single-block exclusive scan of 1563 bucket counts ----------
__global__ __launch_bounds__(256) void bscan(
    const int* __restrict__ bhistP, int* __restrict__ boff, int* __restrict__ curP)
{
    __shared__ int tmp[256];
    __shared__ int carry;
    int tid = threadIdx.x;
    if (tid == 0) carry = 0;
    __syncthreads();
    for (int base = 0; base < NBKT; base += 256) {
        int i = base + tid;
        int v = (i < NBKT) ? bhistP[i * PAD] : 0;
        tmp[tid] = v;
        __syncthreads();
        for (int off = 1; off < 256; off <<= 1) {
            int t = (tid >= off) ? tmp[tid - off] : 0;
            __syncthreads();
            tmp[tid] += t;
            __syncthreads();
        }
        if (i < NBKT) {
            int ex = carry + tmp[tid] - v;
            boff[i] = ex;
            curP[i * PAD] = ex;
        }
        __syncthreads();
        if (tid == 255) carry += tmp[255];
        __syncthreads();
    }
    if (tid < 8) boff[NBKT + tid] = N_EDGES;   // sentinels for 4-bucket blocks
}

// ---------- coarse scatter: packed (src<<6 | dst&63) into bucket segments ----------
__global__ __launch_bounds__(256) void bin_fill(
    const int* __restrict__ eidx, int* __restrict__ curP,
    unsigned int* __restrict__ pairs)
{
    int e = blockIdx.x * blockDim.x + threadIdx.x;
    if (e >= N_EDGES) return;
    int src = eidx[e];
    int dst = eidx[N_EDGES + e];
    int pos = atomicAdd(&curP[(dst >> 6) * PAD], 1);
    pairs[pos] = ((unsigned int)src << 6) | (unsigned int)(dst & 63);
}

// ---------- fine sort: one block per 4 buckets; emits offs[] and csr[] ----------
// Block's csr output region [boff[4b], boff[4b+4]) is CONTIGUOUS -> dense writes.
__global__ __launch_bounds__(256) void fine_sort(
    const unsigned int* __restrict__ pairs,
    const int* __restrict__ boff,
    int* __restrict__ offs,
    int* __restrict__ csr)
{
    __shared__ int cnt[256];
    __shared__ int pfx[256];
    __shared__ int lcur[256];
    __shared__ int sB[5];

    const int tid = threadIdx.x;
    const int b0  = blockIdx.x * 4;
    if (tid < 5) sB[tid] = boff[b0 + tid];
    cnt[tid] = 0;
    __syncthreads();

    const int rbase = sB[0], rend = sB[4];
    for (int j = rbase + tid; j < rend; j += 256) {
        unsigned int p = pairs[j];
        int k = (j >= sB[1]) + (j >= sB[2]) + (j >= sB[3]);
        atomicAdd(&cnt[(k << 6) | (p & 63)], 1);
    }
    __syncthreads();

    int v = cnt[tid];
    pfx[tid] = v;
    __syncthreads();
    for (int off = 1; off < 256; off <<= 1) {
        int t = (tid >= off) ? pfx[tid - off] : 0;
        __syncthreads();
        pfx[tid] += t;
        __syncthreads();
    }
    int ex = pfx[tid] - v;
    lcur[tid] = ex;
    int gn = b0 * 64 + tid;
    if (gn < N_NODES) offs[gn] = rbase + ex;
    if (gn == 0) offs[N_NODES] = N_EDGES;
    __syncthreads();

    for (int j = rbase + tid; j < rend; j += 256) {
        unsigned int p = pairs[j];
        int k = (j >= sB[1]) + (j >= sB[2]) + (j >= sB[3]);
        int ln = (k << 6) | (p & 63);
        int pos = rbase + atomicAdd(&lcur[ln], 1);
        csr[pos] = (int)(p >> 6);
    }
}

// ---------- aggregation: wave per node, lane = feature dim ----------
__global__ __launch_bounds__(256) void aggregate(
    const float* __restrict__ feat,
    const int* __restrict__ offs,
    const int* __restrict__ csr,
    float* __restrict__ out)
{
    const int lane = threadIdx.x & 63;
    const int n = blockIdx.x * 4 + (threadIdx.x >> 6);
    if (n >= N_NODES) return;

    const int beg = offs[n];
    const int end = offs[n + 1];

    float s = 0.0f;
    int e = beg;
    for (; e + 8 <= end; e += 8) {
        int i0 = csr[e], i1 = csr[e+1], i2 = csr[e+2], i3 = csr[e+3];
        int i4 = csr[e+4], i5 = csr[e+5], i6 = csr[e+6], i7 = csr[e+7];
        float a0 = feat[(size_t)i0 * D + lane];
        float a1 = feat[(size_t)i1 * D + lane];
        float a2 = feat[(size_t)i2 * D + lane];
        float a3 = feat[(size_t)i3 * D + lane];
        float a4 = feat[(size_t)i4 * D + lane];
        float a5 = feat[(size_t)i5 * D + lane];
        float a6 = feat[(size_t)i6 * D + lane];
        float a7 = feat[(size_t)i7 * D + lane];
        s += ((a0 + a1) + (a2 + a3)) + ((a4 + a5) + (a6 + a7));
    }
    for (; e < end; ++e) s += feat[(size_t)csr[e] * D + lane];

    float dg = (float)(end - beg);
    dg = dg > 1.0f ? dg : 1.0f;
    out[(size_t)n * D + lane] = s / dg;
}

// ---------- fused linear: LDS-tiled GEMM, block = 64 nodes x 64 cols ----------
#define XS 132
__global__ __launch_bounds__(256) void sage_gemm(
    const float* __restrict__ feat,
    const float* __restrict__ W,
    const float* __restrict__ bias,
    float* __restrict__ out)
{
    __shared__ float X[64 * XS];
    __shared__ float Ws[128 * 64];

    const int tid = threadIdx.x;
    const int nb  = blockIdx.x * 64;

    {
        const float4* Wv  = (const float4*)W;
        float4* Wsv = (float4*)Ws;
        #pragma unroll
        for (int r = 0; r < 8; ++r)
            Wsv[r * 256 + tid] = Wv[r * 256 + tid];
    }
    {
        const int sn = tid >> 4;
        const int kc = tid & 15;
        #pragma unroll
        for (int r = 0; r < 4; ++r) {
            int node = r * 16 + sn;
            int gn = nb + node;
            float4 f = make_float4(0.f, 0.f, 0.f, 0.f);
            float4 m = make_float4(0.f, 0.f, 0.f, 0.f);
            if (gn < N_NODES) {
                f = *(const float4*)(feat + (size_t)gn * 64 + kc * 4);
                m = *(const float4*)(out  + (size_t)gn * 64 + kc * 4);
            }
            *(float4*)(X + node * XS + kc * 4)      = f;
            *(float4*)(X + node * XS + 64 + kc * 4) = m;
        }
    }
    __syncthreads();

    const int ng = tid >> 4;
    const int cg = tid & 15;

    const float4 b4 = *(const float4*)(bias + cg * 4);
    float acc[4][4];
    #pragma unroll
    for (int i = 0; i < 4; ++i) {
        acc[i][0] = b4.x; acc[i][1] = b4.y; acc[i][2] = b4.z; acc[i][3] = b4.w;
    }

    const float* x0p = X + (ng * 4 + 0) * XS;
    const float* x1p = X + (ng * 4 + 1) * XS;
    const float* x2p = X + (ng * 4 + 2) * XS;
    const float* x3p = X + (ng * 4 + 3) * XS;
    const float4* Wrow = (const float4*)Ws;

    #pragma unroll 8
    for (int k = 0; k < 128; ++k) {
        float4 w4 = Wrow[k * 16 + cg];
        float x0 = x0p[k];
        float x1 = x1p[k];
        float x2 = x2p[k];
        float x3 = x3p[k];
        acc[0][0] = fmaf(x0, w4.x, acc[0][0]);
        acc[0][1] = fmaf(x0, w4.y, acc[0][1]);
        acc[0][2] = fmaf(x0, w4.z, acc[0][2]);
        acc[0][3] = fmaf(x0, w4.w, acc[0][3]);
        acc[1][0] = fmaf(x1, w4.x, acc[1][0]);
        acc[1][1] = fmaf(x1, w4.y, acc[1][1]);
        acc[1][2] = fmaf(x1, w4.z, acc[1][2]);
        acc[1][3] = fmaf(x1, w4.w, acc[1][3]);
        acc[2][0] = fmaf(x2, w4.x, acc[2][0]);
        acc[2][1] = fmaf(x2, w4.y, acc[2][1]);
        acc[2][2] = fmaf(x2, w4.z, acc[2][2]);
        acc[2][3] = fmaf(x2, w4.w, acc[2][3]);
        acc[3][0] = fmaf(x3, w4.x, acc[3][0]);
        acc[3][1] = fmaf(x3, w4.y, acc[3][1]);
        acc[3][2] = fmaf(x3, w4.z, acc[3][2]);
        acc[3][3] = fmaf(x3, w4.w, acc[3][3]);
    }

    #pragma unroll
    for (int i = 0; i < 4; ++i) {
        int gn = nb + ng * 4 + i;
        if (gn < N_NODES) {
            float4 o = make_float4(acc[i][0], acc[i][1], acc[i][2], acc[i][3]);
            *(float4*)(out + (size_t)gn * 64 + cg * 4) = o;
        }
    }
}

extern "C" void kernel_launch(void* const* d_in, const int* in_sizes, int n_in,
                              void* d_out, int out_size, void* d_ws, size_t ws_size,
                              hipStream_t stream) {
    const float* feat = (const float*)d_in[0];
    const int*   eidx = (const int*)d_in[1];
    const float* W    = (const float*)d_in[2];
    const float* bias = (const float*)d_in[3];
    float* out = (float*)d_out;

    // workspace layout (ints)
    int* bhistP = (int*)d_ws;                          // NBKT*PAD (padded)
    int* curP   = bhistP + NBKT * PAD;                 // NBKT*PAD (padded)
    int* boff   = curP + NBKT * PAD;                   // NBKT + 8
    int* offs   = boff + NBKT + 8;                     // N_NODES + 1
    unsigned int* pairs = (unsigned int*)(offs + N_NODES + 1);  // N_EDGES
    int* csr    = (int*)(pairs + N_EDGES);             // N_EDGES

    hipMemsetAsync(bhistP, 0, (size_t)NBKT * PAD * sizeof(int), stream);

    bin_hist<<<304, 256, 0, stream>>>(eidx, bhistP);
    bscan<<<1, 256, 0, stream>>>(bhistP, boff, curP);
    bin_fill<<<(N_EDGES + 255) / 256, 256, 0, stream>>>(eidx, curP, pairs);
    fine_sort<<<FSB, 256, 0, stream>>>(pairs, boff, offs, csr);

    aggregate<<<(N_NODES + 3) / 4, 256, 0, stream>>>(feat, offs, csr, out);
    sage_gemm<<<(N_NODES + 63) / 64, 256, 0, stream>>>(feat, W, bias, out);
}

// Round 6
// 164.361 us; speedup vs baseline: 5.2534x; 1.3432x over previous
//
#include <hip/hip_runtime.h>

#define N_NODES 100000
#define D 64
#define N_EDGES 1200000
#define NCB 98               // coarse buckets of 1024 dst nodes: ceil(100000/1024)
#define NBLK 128             // partition blocks
#define CHUNK ((N_EDGES + NBLK - 1) / NBLK)   // 9375 edges per block

// ---------- pass 1: per-block coarse histogram (dense writes) ----------
__global__ __launch_bounds__(256) void bin_hist(
    const int* __restrict__ eidx, int* __restrict__ hist)
{
    __shared__ int h[NCB];
    for (int i = threadIdx.x; i < NCB; i += 256) h[i] = 0;
    __syncthreads();
    const int blk = blockIdx.x;
    const int beg = blk * CHUNK;
    const int end = min(beg + CHUNK, N_EDGES);
    for (int e = beg + threadIdx.x; e < end; e += 256)
        atomicAdd(&h[eidx[N_EDGES + e] >> 10], 1);
    __syncthreads();
    for (int i = threadIdx.x; i < NCB; i += 256) hist[blk * NCB + i] = h[i];
}

// ---------- pass 2: bucket bases + per-(block,bucket) run starts ----------
__global__ __launch_bounds__(128) void bscan(
    const int* __restrict__ hist, int* __restrict__ boff,
    int* __restrict__ runstart, int* __restrict__ offs)
{
    __shared__ int tot[NCB];
    __shared__ int bo[NCB + 1];
    const int t = threadIdx.x;
    if (t < NCB) {
        int s = 0;
        #pragma unroll 4
        for (int blk = 0; blk < NBLK; ++blk) s += hist[blk * NCB + t];
        tot[t] = s;
    }
    __syncthreads();
    if (t == 0) {
        int run = 0;
        for (int b = 0; b < NCB; ++b) { bo[b] = run; run += tot[b]; }
        bo[NCB] = run;                 // == N_EDGES
        offs[N_NODES] = N_EDGES;       // sentinel for aggregate
    }
    __syncthreads();
    if (t < NCB + 1) boff[t] = bo[t];
    if (t < NCB) {
        int run = bo[t];
        #pragma unroll 4
        for (int blk = 0; blk < NBLK; ++blk) {
            runstart[blk * NCB + t] = run;
            run += hist[blk * NCB + t];
        }
    }
}

// ---------- pass 3: deterministic scatter into per-block sub-ranges ----------
__global__ __launch_bounds__(256) void bin_fill(
    const int* __restrict__ eidx, const int* __restrict__ runstart,
    unsigned int* __restrict__ pairs)
{
    __shared__ int lcur[NCB];
    const int blk = blockIdx.x;
    for (int i = threadIdx.x; i < NCB; i += 256) lcur[i] = runstart[blk * NCB + i];
    __syncthreads();
    const int beg = blk * CHUNK;
    const int end = min(beg + CHUNK, N_EDGES);
    for (int e = beg + threadIdx.x; e < end; e += 256) {
        int src = eidx[e];
        int dst = eidx[N_EDGES + e];
        int pos = atomicAdd(&lcur[dst >> 10], 1);
        pairs[pos] = ((unsigned int)src << 10) | (unsigned int)(dst & 1023);
    }
}

// ---------- pass 4: fine sort within coarse bucket -> offs[] + csr[] ----------
// One block per coarse bucket; output region [boff[b], boff[b+1]) is contiguous.
__global__ __launch_bounds__(256) void fine_sort(
    const unsigned int* __restrict__ pairs,
    const int* __restrict__ boff,
    int* __restrict__ offs,
    int* __restrict__ csr)
{
    __shared__ int cnt[1024];
    __shared__ int part[256];

    const int tid = threadIdx.x;
    const int b   = blockIdx.x;
    const int beg = boff[b];
    const int end = boff[b + 1];

    for (int i = tid; i < 1024; i += 256) cnt[i] = 0;
    __syncthreads();

    for (int j = beg + tid; j < end; j += 256)
        atomicAdd(&cnt[pairs[j] & 1023], 1);
    __syncthreads();

    // exclusive scan over 1024 counters (4 per thread + block scan of partials)
    int c0 = cnt[tid * 4 + 0], c1 = cnt[tid * 4 + 1];
    int c2 = cnt[tid * 4 + 2], c3 = cnt[tid * 4 + 3];
    int sum = c0 + c1 + c2 + c3;
    part[tid] = sum;
    __syncthreads();
    for (int off = 1; off < 256; off <<= 1) {
        int t = (tid >= off) ? part[tid - off] : 0;
        __syncthreads();
        part[tid] += t;
        __syncthreads();
    }
    int e0 = part[tid] - sum;
    int e1 = e0 + c0, e2 = e1 + c1, e3 = e2 + c2;

    const int gbase = b * 1024 + tid * 4;
    if (gbase + 0 < N_NODES) offs[gbase + 0] = beg + e0;
    if (gbase + 1 < N_NODES) offs[gbase + 1] = beg + e1;
    if (gbase + 2 < N_NODES) offs[gbase + 2] = beg + e2;
    if (gbase + 3 < N_NODES) offs[gbase + 3] = beg + e3;

    cnt[tid * 4 + 0] = e0; cnt[tid * 4 + 1] = e1;
    cnt[tid * 4 + 2] = e2; cnt[tid * 4 + 3] = e3;
    __syncthreads();

    for (int j = beg + tid; j < end; j += 256) {
        unsigned int p = pairs[j];
        int pos = beg + atomicAdd(&cnt[p & 1023], 1);
        csr[pos] = (int)(p >> 10);
    }
}

// ---------- aggregation: wave per node, lane = feature dim ----------
__global__ __launch_bounds__(256) void aggregate(
    const float* __restrict__ feat,
    const int* __restrict__ offs,
    const int* __restrict__ csr,
    float* __restrict__ out)
{
    const int lane = threadIdx.x & 63;
    const int n = blockIdx.x * 4 + (threadIdx.x >> 6);
    if (n >= N_NODES) return;

    const int beg = offs[n];
    const int end = offs[n + 1];

    float s = 0.0f;
    int e = beg;
    for (; e + 8 <= end; e += 8) {
        int i0 = csr[e], i1 = csr[e+1], i2 = csr[e+2], i3 = csr[e+3];
        int i4 = csr[e+4], i5 = csr[e+5], i6 = csr[e+6], i7 = csr[e+7];
        float a0 = feat[(size_t)i0 * D + lane];
        float a1 = feat[(size_t)i1 * D + lane];
        float a2 = feat[(size_t)i2 * D + lane];
        float a3 = feat[(size_t)i3 * D + lane];
        float a4 = feat[(size_t)i4 * D + lane];
        float a5 = feat[(size_t)i5 * D + lane];
        float a6 = feat[(size_t)i6 * D + lane];
        float a7 = feat[(size_t)i7 * D + lane];
        s += ((a0 + a1) + (a2 + a3)) + ((a4 + a5) + (a6 + a7));
    }
    for (; e < end; ++e) s += feat[(size_t)csr[e] * D + lane];

    float dg = (float)(end - beg);
    dg = dg > 1.0f ? dg : 1.0f;
    out[(size_t)n * D + lane] = s / dg;
}

// ---------- fused linear: LDS-tiled GEMM, block = 64 nodes x 64 cols ----------
#define XS 132
__global__ __launch_bounds__(256) void sage_gemm(
    const float* __restrict__ feat,
    const float* __restrict__ W,
    const float* __restrict__ bias,
    float* __restrict__ out)
{
    __shared__ float X[64 * XS];
    __shared__ float Ws[128 * 64];

    const int tid = threadIdx.x;
    const int nb  = blockIdx.x * 64;

    {
        const float4* Wv  = (const float4*)W;
        float4* Wsv = (float4*)Ws;
        #pragma unroll
        for (int r = 0; r < 8; ++r)
            Wsv[r * 256 + tid] = Wv[r * 256 + tid];
    }
    {
        const int sn = tid >> 4;
        const int kc = tid & 15;
        #pragma unroll
        for (int r = 0; r < 4; ++r) {
            int node = r * 16 + sn;
            int gn = nb + node;
            float4 f = make_float4(0.f, 0.f, 0.f, 0.f);
            float4 m = make_float4(0.f, 0.f, 0.f, 0.f);
            if (gn < N_NODES) {
                f = *(const float4*)(feat + (size_t)gn * 64 + kc * 4);
                m = *(const float4*)(out  + (size_t)gn * 64 + kc * 4);
            }
            *(float4*)(X + node * XS + kc * 4)      = f;
            *(float4*)(X + node * XS + 64 + kc * 4) = m;
        }
    }
    __syncthreads();

    const int ng = tid >> 4;
    const int cg = tid & 15;

    const float4 b4 = *(const float4*)(bias + cg * 4);
    float acc[4][4];
    #pragma unroll
    for (int i = 0; i < 4; ++i) {
        acc[i][0] = b4.x; acc[i][1] = b4.y; acc[i][2] = b4.z; acc[i][3] = b4.w;
    }

    const float* x0p = X + (ng * 4 + 0) * XS;
    const float* x1p = X + (ng * 4 + 1) * XS;
    const float* x2p = X + (ng * 4 + 2) * XS;
    const float* x3p = X + (ng * 4 + 3) * XS;
    const float4* Wrow = (const float4*)Ws;

    #pragma unroll 8
    for (int k = 0; k < 128; ++k) {
        float4 w4 = Wrow[k * 16 + cg];
        float x0 = x0p[k];
        float x1 = x1p[k];
        float x2 = x2p[k];
        float x3 = x3p[k];
        acc[0][0] = fmaf(x0, w4.x, acc[0][0]);
        acc[0][1] = fmaf(x0, w4.y, acc[0][1]);
        acc[0][2] = fmaf(x0, w4.z, acc[0][2]);
        acc[0][3] = fmaf(x0, w4.w, acc[0][3]);
        acc[1][0] = fmaf(x1, w4.x, acc[1][0]);
        acc[1][1] = fmaf(x1, w4.y, acc[1][1]);
        acc[1][2] = fmaf(x1, w4.z, acc[1][2]);
        acc[1][3] = fmaf(x1, w4.w, acc[1][3]);
        acc[2][0] = fmaf(x2, w4.x, acc[2][0]);
        acc[2][1] = fmaf(x2, w4.y, acc[2][1]);
        acc[2][2] = fmaf(x2, w4.z, acc[2][2]);
        acc[2][3] = fmaf(x2, w4.w, acc[2][3]);
        acc[3][0] = fmaf(x3, w4.x, acc[3][0]);
        acc[3][1] = fmaf(x3, w4.y, acc[3][1]);
        acc[3][2] = fmaf(x3, w4.z, acc[3][2]);
        acc[3][3] = fmaf(x3, w4.w, acc[3][3]);
    }

    #pragma unroll
    for (int i = 0; i < 4; ++i) {
        int gn = nb + ng * 4 + i;
        if (gn < N_NODES) {
            float4 o = make_float4(acc[i][0], acc[i][1], acc[i][2], acc[i][3]);
            *(float4*)(out + (size_t)gn * 64 + cg * 4) = o;
        }
    }
}

extern "C" void kernel_launch(void* const* d_in, const int* in_sizes, int n_in,
                              void* d_out, int out_size, void* d_ws, size_t ws_size,
                              hipStream_t stream) {
    const float* feat = (const float*)d_in[0];
    const int*   eidx = (const int*)d_in[1];
    const float* W    = (const float*)d_in[2];
    const float* bias = (const float*)d_in[3];
    float* out = (float*)d_out;

    // workspace layout (ints) — every array fully written before read, no memset
    int* hist     = (int*)d_ws;                        // NBLK*NCB
    int* runstart = hist + NBLK * NCB;                 // NBLK*NCB
    int* boff     = runstart + NBLK * NCB;             // NCB + 1 (+pad)
    int* offs     = boff + NCB + 2;                    // N_NODES + 1
    unsigned int* pairs = (unsigned int*)(offs + N_NODES + 1);  // N_EDGES
    int* csr      = (int*)(pairs + N_EDGES);           // N_EDGES

    bin_hist<<<NBLK, 256, 0, stream>>>(eidx, hist);
    bscan<<<1, 128, 0, stream>>>(hist, boff, runstart, offs);
    bin_fill<<<NBLK, 256, 0, stream>>>(eidx, runstart, pairs);
    fine_sort<<<NCB, 256, 0, stream>>>(pairs, boff, offs, csr);

    aggregate<<<(N_NODES + 3) / 4, 256, 0, stream>>>(feat, offs, csr, out);
    sage_gemm<<<(N_NODES + 63) / 64, 256, 0, stream>>>(feat, W, bias, out);
}